// Round 10
// baseline (3456.303 us; speedup 1.0000x reference)
//
#include <hip/hip_runtime.h>
#include <hip/hip_bf16.h>
#include <cstdint>

#define RR 512          // B*K rows
#define KB_ 8           // beams
#define VV 400          // vocab
#define HD_ 1024
#define GD 4096         // 4*HD
#define LL 13           // program_len
#define BKT 16          // GEMM K-tile
#define NPTS 1000       // integration points
#define OUT_N 18560
#define LDP 68          // padded LDS leading dim

// unordered pair tables (j<l) for the 28 off-diagonal logsumexp reductions
__device__ __constant__ int cPJ[28] = {0,0,0,0,0,0,0,1,1,1,1,1,1,2,2,2,2,2,3,3,3,3,4,4,4,5,5,6};
__device__ __constant__ int cPL[28] = {1,2,3,4,5,6,7,2,3,4,5,6,7,3,4,5,6,7,4,5,6,7,5,6,7,6,7,7};

__device__ __forceinline__ float rA_log1mexp(float x) {
  x = fminf(x, -1e-38f);
  return (x > -0.6931472f) ? logf(-expm1f(x)) : log1pf(-expf(x));
}

__device__ __forceinline__ float rA_sigm(float x) { return 1.f / (1.f + expf(-x)); }

__device__ __forceinline__ int rA_pidx(int j, int l) {
  if (j > l) { int t = j; j = l; l = t; }
  return 9 + (j * (15 - j)) / 2 + (l - j - 1);
}

__device__ __forceinline__ float rA_wmax(float v) {
  #pragma unroll
  for (int o = 32; o; o >>= 1) v = fmaxf(v, __shfl_xor(v, o, 64));
  return v;
}

__device__ __forceinline__ float rA_wsum(float v) {
  #pragma unroll
  for (int o = 32; o; o >>= 1) v += __shfl_xor(v, o, 64);
  return v;
}

// ---- zero carried state ----
__global__ __launch_bounds__(256) void rA_wszero(float* h0, float* c0, float* Gv,
                                                 float* logp0, float* accum) {
  int idx = blockIdx.x * 256 + threadIdx.x;
  if (idx < RR * HD_) { h0[idx] = 0.f; c0[idx] = 0.f; }
  if (idx < RR) { Gv[idx] = 0.f; logp0[idx] = 0.f; }
  if (idx < 128) accum[idx] = 0.f;
}

__global__ __launch_bounds__(256) void rA_flag(float* dout) {
  int idx = blockIdx.x * 256 + threadIdx.x;
  if (idx < OUT_N) dout[idx] = (idx == 6656) ? 20000.0f : 0.0f;
}

// xfb once: 64x64 tile, 256 threads, 4x4 acc (one-time cost, keep simple)
__global__ __launch_bounds__(256) void rA_xfb(const float* __restrict__ xf,
                                              const float* __restrict__ Wih,
                                              const float* __restrict__ bih,
                                              const float* __restrict__ bhh,
                                              float* __restrict__ xfb) {
  __shared__ __align__(16) float As[BKT][LDP];
  __shared__ __align__(16) float Bs[BKT][LDP];
  float acc[4][4] = {};
  const int tid = threadIdx.x;
  const int n0 = blockIdx.x * 64;
  const int la = tid >> 2, lk = (tid & 3) << 2;
  const int tx = tid & 15, ty = tid >> 4;
  for (int k0 = 0; k0 < 1024; k0 += BKT) {
    float4 av = *reinterpret_cast<const float4*>(xf + (size_t)la * 1024 + k0 + lk);
    float4 bv = *reinterpret_cast<const float4*>(Wih + (size_t)(n0 + la) * 1152 + k0 + lk);
    __syncthreads();
    As[lk + 0][la] = av.x; As[lk + 1][la] = av.y; As[lk + 2][la] = av.z; As[lk + 3][la] = av.w;
    Bs[lk + 0][la] = bv.x; Bs[lk + 1][la] = bv.y; Bs[lk + 2][la] = bv.z; Bs[lk + 3][la] = bv.w;
    __syncthreads();
    #pragma unroll
    for (int kk = 0; kk < BKT; ++kk) {
      float4 a = *reinterpret_cast<const float4*>(&As[kk][ty * 4]);
      float4 b = *reinterpret_cast<const float4*>(&Bs[kk][tx * 4]);
      float ar[4] = {a.x, a.y, a.z, a.w};
      float br[4] = {b.x, b.y, b.z, b.w};
      #pragma unroll
      for (int i = 0; i < 4; ++i)
        #pragma unroll
        for (int j = 0; j < 4; ++j)
          acc[i][j] = fmaf(ar[i], br[j], acc[i][j]);
    }
  }
  #pragma unroll
  for (int i = 0; i < 4; ++i)
    #pragma unroll
    for (int j = 0; j < 4; ++j) {
      int r = ty * 4 + i, c = n0 + tx * 4 + j;
      xfb[(size_t)r * GD + c] = acc[i][j] + bih[c] + bhh[c];
    }
}

// gates GEMM: 64r x 64c x 1 gate, 128 threads, 4x8 acc; grid (16,8,4)=512 blocks.
// A rows gathered via parent order; inp operand inline (one-hot column gather).
__global__ __launch_bounds__(128) void rA_glstm(
    const float* __restrict__ hprev,
    const float* __restrict__ Whh, const float* __restrict__ Wih,
    const float* __restrict__ Wio, const float* __restrict__ bio,
    const int* __restrict__ s_arr, const int* __restrict__ o_arr, int t,
    float* __restrict__ gates)
{
  __shared__ __align__(16) float As[BKT][LDP];
  __shared__ __align__(16) float Bs[BKT][LDP];
  float acc[4][8] = {};
  const int tid = threadIdx.x;
  const int c0 = blockIdx.x * 64;         // col offset within gate
  const int r0 = blockIdx.y * 64;
  const int g  = blockIdx.z;
  const int sr = tid >> 1;                // staging row/col 0..63
  const int sk = (tid & 1) * 8;           // staging k offset 0 or 8
  const int tx = tid & 7, ty = tid >> 3;  // cols tx*8, rows ty*4
  const int arow = r0 + sr;
  const int asrc = (t == 0) ? arow : o_arr[(size_t)(t - 1) * RR + arow];
  const int s_row = (t == 0) ? 400 : s_arr[(size_t)(t - 1) * RR + arow];
  const float* Arow = hprev + (size_t)asrc * HD_;
  const float* Brow = Whh + (size_t)(g * 1024 + c0 + sr) * HD_;
  for (int k0 = 0; k0 < HD_; k0 += BKT) {
    float4 a0 = *reinterpret_cast<const float4*>(Arow + k0 + sk);
    float4 a1 = *reinterpret_cast<const float4*>(Arow + k0 + sk + 4);
    float4 b0 = *reinterpret_cast<const float4*>(Brow + k0 + sk);
    float4 b1 = *reinterpret_cast<const float4*>(Brow + k0 + sk + 4);
    __syncthreads();
    As[sk + 0][sr] = a0.x; As[sk + 1][sr] = a0.y; As[sk + 2][sr] = a0.z; As[sk + 3][sr] = a0.w;
    As[sk + 4][sr] = a1.x; As[sk + 5][sr] = a1.y; As[sk + 6][sr] = a1.z; As[sk + 7][sr] = a1.w;
    Bs[sk + 0][sr] = b0.x; Bs[sk + 1][sr] = b0.y; Bs[sk + 2][sr] = b0.z; Bs[sk + 3][sr] = b0.w;
    Bs[sk + 4][sr] = b1.x; Bs[sk + 5][sr] = b1.y; Bs[sk + 6][sr] = b1.z; Bs[sk + 7][sr] = b1.w;
    __syncthreads();
    #pragma unroll
    for (int kk = 0; kk < BKT; ++kk) {
      float4 a = *reinterpret_cast<const float4*>(&As[kk][ty * 4]);
      float4 bA = *reinterpret_cast<const float4*>(&Bs[kk][tx * 8]);
      float4 bB = *reinterpret_cast<const float4*>(&Bs[kk][tx * 8 + 4]);
      float ar[4] = {a.x, a.y, a.z, a.w};
      float br[8] = {bA.x, bA.y, bA.z, bA.w, bB.x, bB.y, bB.z, bB.w};
      #pragma unroll
      for (int i = 0; i < 4; ++i)
        #pragma unroll
        for (int j = 0; j < 8; ++j)
          acc[i][j] = fmaf(ar[i], br[j], acc[i][j]);
    }
  }
  // inp segment: K=128; A element = relu(Wio[m*401 + s_row] + bio[m])
  const float* BrowI = Wih + (size_t)(g * 1024 + c0 + sr) * 1152 + 1024;
  for (int k0 = 0; k0 < 128; k0 += BKT) {
    float av[8];
    #pragma unroll
    for (int m = 0; m < 8; ++m) {
      int mm = k0 + sk + m;
      av[m] = fmaxf(Wio[(size_t)mm * 401 + s_row] + bio[mm], 0.f);
    }
    float4 b0 = *reinterpret_cast<const float4*>(BrowI + k0 + sk);
    float4 b1 = *reinterpret_cast<const float4*>(BrowI + k0 + sk + 4);
    __syncthreads();
    #pragma unroll
    for (int m = 0; m < 8; ++m) As[sk + m][sr] = av[m];
    Bs[sk + 0][sr] = b0.x; Bs[sk + 1][sr] = b0.y; Bs[sk + 2][sr] = b0.z; Bs[sk + 3][sr] = b0.w;
    Bs[sk + 4][sr] = b1.x; Bs[sk + 5][sr] = b1.y; Bs[sk + 6][sr] = b1.z; Bs[sk + 7][sr] = b1.w;
    __syncthreads();
    #pragma unroll
    for (int kk = 0; kk < BKT; ++kk) {
      float4 a = *reinterpret_cast<const float4*>(&As[kk][ty * 4]);
      float4 bA = *reinterpret_cast<const float4*>(&Bs[kk][tx * 8]);
      float4 bB = *reinterpret_cast<const float4*>(&Bs[kk][tx * 8 + 4]);
      float ar[4] = {a.x, a.y, a.z, a.w};
      float br[8] = {bA.x, bA.y, bA.z, bA.w, bB.x, bB.y, bB.z, bB.w};
      #pragma unroll
      for (int i = 0; i < 4; ++i)
        #pragma unroll
        for (int j = 0; j < 8; ++j)
          acc[i][j] = fmaf(ar[i], br[j], acc[i][j]);
    }
  }
  #pragma unroll
  for (int i = 0; i < 4; ++i) {
    float* dst = gates + (size_t)(r0 + ty * 4 + i) * GD + g * 1024 + c0 + tx * 8;
    *reinterpret_cast<float4*>(dst) = make_float4(acc[i][0], acc[i][1], acc[i][2], acc[i][3]);
    *reinterpret_cast<float4*>(dst + 4) = make_float4(acc[i][4], acc[i][5], acc[i][6], acc[i][7]);
  }
}

// LSTM pointwise: + xfb, gathered c_prev
__global__ __launch_bounds__(256) void rA_lstm(const float* gates, const float* xfb,
                                               const float* cprev, const int* o_arr, int t,
                                               float* cout, float* hout) {
  int idx = blockIdx.x * 256 + threadIdx.x;   // 512*1024
  int r = idx >> 10, n = idx & 1023;
  int src = (t == 0) ? r : o_arr[(size_t)(t - 1) * RR + r];
  const float* g = gates + (size_t)r * GD;
  const float* xb = xfb + (size_t)(r & 63) * GD;
  float gi = g[n] + xb[n];
  float gf = g[1024 + n] + xb[1024 + n];
  float gg = g[2048 + n] + xb[2048 + n];
  float go = g[3072 + n] + xb[3072 + n];
  float cp = cprev[(size_t)src * HD_ + n];
  float c = rA_sigm(gf) * cp + rA_sigm(gi) * tanhf(gg);
  cout[idx] = c;
  hout[idx] = rA_sigm(go) * tanhf(c);
}

// fc1: 64x64, 128 thr, 4x8 acc, K-split z=2 (K=512 each); partial -> hdp[z]
__global__ __launch_bounds__(128) void rA_fc1(const float* __restrict__ h,
                                              const float* __restrict__ W1, float* hdp) {
  __shared__ __align__(16) float As[BKT][LDP];
  __shared__ __align__(16) float Bs[BKT][LDP];
  float acc[4][8] = {};
  const int tid = threadIdx.x;
  const int n0 = blockIdx.x * 64, r0 = blockIdx.y * 64, z = blockIdx.z;
  const int sr = tid >> 1, sk = (tid & 1) * 8;
  const int tx = tid & 7, ty = tid >> 3;
  const float* Arow = h + (size_t)(r0 + sr) * HD_ + z * 512;
  const float* Brow = W1 + (size_t)(n0 + sr) * HD_ + z * 512;
  for (int k0 = 0; k0 < 512; k0 += BKT) {
    float4 a0 = *reinterpret_cast<const float4*>(Arow + k0 + sk);
    float4 a1 = *reinterpret_cast<const float4*>(Arow + k0 + sk + 4);
    float4 b0 = *reinterpret_cast<const float4*>(Brow + k0 + sk);
    float4 b1 = *reinterpret_cast<const float4*>(Brow + k0 + sk + 4);
    __syncthreads();
    As[sk + 0][sr] = a0.x; As[sk + 1][sr] = a0.y; As[sk + 2][sr] = a0.z; As[sk + 3][sr] = a0.w;
    As[sk + 4][sr] = a1.x; As[sk + 5][sr] = a1.y; As[sk + 6][sr] = a1.z; As[sk + 7][sr] = a1.w;
    Bs[sk + 0][sr] = b0.x; Bs[sk + 1][sr] = b0.y; Bs[sk + 2][sr] = b0.z; Bs[sk + 3][sr] = b0.w;
    Bs[sk + 4][sr] = b1.x; Bs[sk + 5][sr] = b1.y; Bs[sk + 6][sr] = b1.z; Bs[sk + 7][sr] = b1.w;
    __syncthreads();
    #pragma unroll
    for (int kk = 0; kk < BKT; ++kk) {
      float4 a = *reinterpret_cast<const float4*>(&As[kk][ty * 4]);
      float4 bA = *reinterpret_cast<const float4*>(&Bs[kk][tx * 8]);
      float4 bB = *reinterpret_cast<const float4*>(&Bs[kk][tx * 8 + 4]);
      float ar[4] = {a.x, a.y, a.z, a.w};
      float br[8] = {bA.x, bA.y, bA.z, bA.w, bB.x, bB.y, bB.z, bB.w};
      #pragma unroll
      for (int i = 0; i < 4; ++i)
        #pragma unroll
        for (int j = 0; j < 8; ++j)
          acc[i][j] = fmaf(ar[i], br[j], acc[i][j]);
    }
  }
  float* base = hdp + (size_t)z * RR * HD_;
  #pragma unroll
  for (int i = 0; i < 4; ++i) {
    float* dst = base + (size_t)(r0 + ty * 4 + i) * HD_ + n0 + tx * 8;
    *reinterpret_cast<float4*>(dst) = make_float4(acc[i][0], acc[i][1], acc[i][2], acc[i][3]);
    *reinterpret_cast<float4*>(dst + 4) = make_float4(acc[i][4], acc[i][5], acc[i][6], acc[i][7]);
  }
}

// out: 64x64, 128 thr, 4x8 acc, K-split z=4 (K=256); A = relu(hdp0+hdp1+b1) inline.
__global__ __launch_bounds__(128) void rA_out(const float* __restrict__ hdp,
                                              const float* __restrict__ b1,
                                              const float* __restrict__ Wo, float* outp) {
  __shared__ __align__(16) float As[BKT][LDP];
  __shared__ __align__(16) float Bs[BKT][LDP];
  float acc[4][8] = {};
  const int tid = threadIdx.x;
  const int n0 = blockIdx.x * 64, r0 = blockIdx.y * 64, z = blockIdx.z;
  const int sr = tid >> 1, sk = (tid & 1) * 8;
  const int tx = tid & 7, ty = tid >> 3;
  const size_t arow_off = (size_t)(r0 + sr) * HD_ + z * 256;
  const int bcol = n0 + sr;
  const float* Brow = Wo + (size_t)bcol * HD_ + z * 256;
  for (int k0 = 0; k0 < 256; k0 += BKT) {
    float av[8];
    #pragma unroll
    for (int m = 0; m < 8; ++m) {
      int kg = z * 256 + k0 + sk + m;
      av[m] = fmaxf(hdp[arow_off + k0 + sk + m] + hdp[RR * HD_ + arow_off + k0 + sk + m]
                    + b1[kg], 0.f);
    }
    float4 b0 = make_float4(0.f, 0.f, 0.f, 0.f), b1v = b0;
    if (bcol < VV) {
      b0  = *reinterpret_cast<const float4*>(Brow + k0 + sk);
      b1v = *reinterpret_cast<const float4*>(Brow + k0 + sk + 4);
    }
    __syncthreads();
    #pragma unroll
    for (int m = 0; m < 8; ++m) As[sk + m][sr] = av[m];
    Bs[sk + 0][sr] = b0.x; Bs[sk + 1][sr] = b0.y; Bs[sk + 2][sr] = b0.z; Bs[sk + 3][sr] = b0.w;
    Bs[sk + 4][sr] = b1v.x; Bs[sk + 5][sr] = b1v.y; Bs[sk + 6][sr] = b1v.z; Bs[sk + 7][sr] = b1v.w;
    __syncthreads();
    #pragma unroll
    for (int kk = 0; kk < BKT; ++kk) {
      float4 a = *reinterpret_cast<const float4*>(&As[kk][ty * 4]);
      float4 bA = *reinterpret_cast<const float4*>(&Bs[kk][tx * 8]);
      float4 bB = *reinterpret_cast<const float4*>(&Bs[kk][tx * 8 + 4]);
      float ar[4] = {a.x, a.y, a.z, a.w};
      float br[8] = {bA.x, bA.y, bA.z, bA.w, bB.x, bB.y, bB.z, bB.w};
      #pragma unroll
      for (int i = 0; i < 4; ++i)
        #pragma unroll
        for (int j = 0; j < 8; ++j)
          acc[i][j] = fmaf(ar[i], br[j], acc[i][j]);
    }
  }
  float* base = outp + (size_t)z * RR * VV;
  #pragma unroll
  for (int i = 0; i < 4; ++i)
    #pragma unroll
    for (int j = 0; j < 8; ++j) {
      int c = n0 + tx * 8 + j;
      if (c < VV) base[(size_t)(r0 + ty * 4 + i) * VV + c] = acc[i][j];
    }
}

// pack (value, index) so u64-max == (max value, tie -> lower index)
__device__ __forceinline__ unsigned long long rA_pack(float v, int c) {
  unsigned u = __float_as_uint(v);
  u = (u & 0x80000000u) ? ~u : (u | 0x80000000u);
  return ((unsigned long long)u << 32) | (unsigned)(0xFFFFFFFFu - (unsigned)c);
}

// fused per-batch: logit-combine + log_softmax + entropy + gumbel-with-max
// + top-8 + selection bookkeeping + compute_log_R + entropy accumulation.
__global__ __launch_bounds__(256) void rA_smax(
    const float* __restrict__ outp, const float* __restrict__ bo,
    const float* __restrict__ logp_in, float* logp_out, float* Gv,
    const float* __restrict__ gum, int* s_t, int* o_t, float* lv_t,
    float* accum, float* dout, int t, int last)
{
  __shared__ __align__(16) float shbuf[9000];   // phase A: gk[3200]+lpl[3200]; phase B: Tm[8][1000]+base[1000]
  __shared__ float entold8[KB_], phi8[KB_], entb8[KB_], pj8[KB_];
  __shared__ float res[37];
  __shared__ unsigned long long wbest[4], selK[KB_];
  float* gk  = shbuf;
  float* lpl = shbuf + 3200;
  const int i = blockIdx.x, tid = threadIdx.x;
  const int lane = tid & 63, wid = tid >> 6;

  // ---- soft phase: 2 rows per wave ----
  for (int rl = wid; rl < KB_; rl += 4) {
    int r = rl * 64 + i;
    float lv_[7];
    float m = -INFINITY;
    #pragma unroll
    for (int ch = 0; ch < 7; ++ch) {
      int n = ch * 64 + lane;
      float l = -INFINITY;
      if (n < VV) {
        size_t off = (size_t)r * VV + n;
        l = outp[off] + outp[RR * VV + off] + outp[2 * RR * VV + off]
          + outp[3 * RR * VV + off] + bo[n];
      }
      lv_[ch] = l;
      m = fmaxf(m, l);
    }
    m = rA_wmax(m);
    float ssum = 0.f;
    #pragma unroll
    for (int ch = 0; ch < 7; ++ch) {
      int n = ch * 64 + lane;
      if (n < VV) ssum += expf(lv_[ch] - m);
    }
    ssum = rA_wsum(ssum);
    float ls = logf(ssum);
    float ent = 0.f;
    #pragma unroll
    for (int ch = 0; ch < 7; ++ch) {
      int n = ch * 64 + lane;
      if (n < VV) {
        float lp = lv_[ch] - m - ls;
        lpl[rl * VV + n] = lp;
        ent += lp * expf(lp);
        lv_[ch] = lp;          // reuse register: now holds lp
      }
    }
    ent = rA_wsum(ent);
    if (lane == 0) entold8[rl] = ent;
    float lpr = logp_in[r];
    const float* ur = gum + (size_t)r * VV;
    float gp_[7];
    float Z = -INFINITY;
    #pragma unroll
    for (int ch = 0; ch < 7; ++ch) {
      int n = ch * 64 + lane;
      float gp = -INFINITY;
      if (n < VV) {
        float u = ur[n];
        gp = lv_[ch] + lpr - logf(-logf(u * (1.f - 2e-7f) + 1e-7f));
      }
      gp_[ch] = gp;
      Z = fmaxf(Z, gp);
    }
    Z = rA_wmax(Z);
    float T = Gv[r];
    #pragma unroll
    for (int ch = 0; ch < 7; ++ch) {
      int n = ch * 64 + lane;
      if (n < VV) {
        float vv = T - gp_[ch] + rA_log1mexp(gp_[ch] - Z);
        gk[rl * VV + n] = T - fmaxf(vv, 0.f) - log1pf(expf(-fabsf(vv)));
      }
    }
  }
  __syncthreads();

  // ---- topk phase ----
  int limit = (t == 0) ? VV : KB_ * VV;
  for (int it = 0; it < KB_; ++it) {
    unsigned long long b = 0ull;
    for (int c = tid; c < limit; c += 256) {
      unsigned long long k = rA_pack(gk[c], c);
      b = (k > b) ? k : b;
    }
    #pragma unroll
    for (int o = 32; o; o >>= 1) {
      unsigned long long x = __shfl_xor(b, o, 64);
      b = (x > b) ? x : b;
    }
    if (lane == 0) wbest[wid] = b;
    __syncthreads();
    unsigned long long g = wbest[0];
    g = (wbest[1] > g) ? wbest[1] : g;
    g = (wbest[2] > g) ? wbest[2] : g;
    g = (wbest[3] > g) ? wbest[3] : g;
    if (tid == 0) {
      int csel = (int)(0xFFFFFFFFu - (unsigned)(g & 0xFFFFFFFFu));
      gk[csel] = -INFINITY;
      selK[it] = g;
    }
    __syncthreads();
  }

  // ---- selection bookkeeping ----
  if (tid < KB_) {
    unsigned long long g = selK[tid];
    unsigned x = (unsigned)(g >> 32);
    x = (x & 0x80000000u) ? (x & 0x7FFFFFFFu) : ~x;
    float v = __uint_as_float(x);
    int c = (int)(0xFFFFFFFFu - (unsigned)(g & 0xFFFFFFFFu));
    int r = tid * 64 + i;
    int s = c % VV;
    int jp = c / VV;               // local parent beam
    int o = jp * 64 + i;
    Gv[r] = v;
    s_t[r] = s;
    o_t[r] = o;
    float lv = lpl[jp * VV + s];
    float ph = logp_in[o] + lv;
    logp_out[r] = ph;
    lv_t[r] = lv;
    phi8[tid] = ph;
    pj8[tid] = expf(ph);
    entb8[tid] = entold8[jp];
  }
  __syncthreads();

  // ---- logR phase (Tm/base overlay gk/lpl) ----
  float (*Tm)[NPTS] = reinterpret_cast<float (*)[NPTS]>(shbuf);
  float* base = shbuf + 8000;
  float pS = ((pj8[0] + pj8[1]) + (pj8[2] + pj8[3])) + ((pj8[4] + pj8[5]) + (pj8[6] + pj8[7]));
  for (int n = tid; n < NPTS; n += 256) {
    float lu = logf((n + 0.5f) * (1.0f / NPTS));
    float b = -pS * lu;
    #pragma unroll
    for (int j = 0; j < KB_; ++j) {
      float tv = rA_log1mexp(pj8[j] * lu);
      Tm[j][n] = tv; b += tv;
    }
    base[n] = b;
  }
  __syncthreads();
  const float logN = 6.9077552789821f;   // log(1000)
  for (int ridx = wid; ridx < 37; ridx += 4) {
    int jj = -1, ll = -1;
    if (ridx >= 1 && ridx < 9) jj = ridx - 1;
    else if (ridx >= 9) { jj = cPJ[ridx - 9]; ll = cPL[ridx - 9]; }
    float mx = -INFINITY;
    for (int n = lane; n < NPTS; n += 64) {
      float v = base[n];
      if (jj >= 0) v -= Tm[jj][n];
      if (ll >= 0) v -= Tm[ll][n];
      mx = fmaxf(mx, v);
    }
    mx = rA_wmax(mx);
    float sm = 0.f;
    for (int n = lane; n < NPTS; n += 64) {
      float v = base[n];
      if (jj >= 0) v -= Tm[jj][n];
      if (ll >= 0) v -= Tm[ll][n];
      sm += expf(v - mx);
    }
    sm = rA_wsum(sm);
    if (lane == 0) res[ridx] = mx + logf(sm) - logN;
  }
  __syncthreads();
  if (tid == 0) {
    float logI = res[0];
    float Wsum = 0.f, ws = 0.f;
    #pragma unroll
    for (int j = 0; j < KB_; ++j) {
      float lRs = res[1 + j] - logI;
      float wj = expf(phi8[j] + lRs);
      Wsum += wj;
      ws += wj * entb8[j];
    }
    accum[i] += ws;               // ent_plot
    accum[64 + i] += ws / Wsum;   // entropy_element
    if (last) {
      for (int j = 0; j < KB_; ++j) {
        dout[13376 + i * 8 + j] = res[1 + j] - logI;     // log_R_s
        dout[17984 + i * 8 + j] = phi8[j];               // phi_k
        for (int l = 0; l < KB_; ++l) {
          float v = (l == j) ? 0.f : (res[rA_pidx(j, l)] - res[1 + j]);
          dout[13888 + i * 64 + j * 8 + l] = v;          // log_R_ss
        }
      }
    }
  }
}

// final: walk ancestor chains, pack all outputs (float32)
__global__ __launch_bounds__(512) void rA_final(const float* lv_arr, const int* s_arr,
                                                const int* o_arr, const float* accum,
                                                float* dout) {
  int r = threadIdx.x;
  int i = r & 63, j = r >> 6;
  float vals[LL]; int svs[LL];
  int a = r;
  for (int tt = LL - 1; tt >= 0; --tt) {
    vals[tt] = lv_arr[tt * RR + a];
    svs[tt]  = s_arr[tt * RR + a];
    a = o_arr[tt * RR + a];
  }
  #pragma unroll
  for (int tt = 0; tt < LL; ++tt) {
    dout[i * 104 + j * 13 + tt] = vals[tt];
    dout[6656 + i * 104 + j * 13 + tt] = (float)svs[tt];
  }
  if (r < 64) {
    dout[13312 + r] = accum[64 + r];   // entropy_element
    dout[18496 + r] = accum[r];        // ent_plot
  }
}

extern "C" void kernel_launch(void* const* d_in, const int* in_sizes, int n_in,
                              void* d_out, int out_size, void* d_ws, size_t ws_size,
                              hipStream_t stream) {
  const float* x_feat  = (const float*)d_in[0];
  const float* W_in_op = (const float*)d_in[1];
  const float* b_in_op = (const float*)d_in[2];
  const float* W_ih    = (const float*)d_in[3];
  const float* W_hh    = (const float*)d_in[4];
  const float* b_ih    = (const float*)d_in[5];
  const float* b_hh    = (const float*)d_in[6];
  const float* W_fc1   = (const float*)d_in[7];
  const float* b_fc1   = (const float*)d_in[8];
  const float* W_out   = (const float*)d_in[9];
  const float* b_out   = (const float*)d_in[10];
  const float* gum     = (const float*)d_in[11];
  float* out           = (float*)d_out;

  float* W = (float*)d_ws;
  size_t o = 0;
  float* lv_arr = W + o; o += (size_t)LL * RR;
  float* Gv     = W + o; o += RR;
  float* logpb0 = W + o; o += RR;
  float* logpb1 = W + o; o += RR;
  float* accum  = W + o; o += 128;
  int* s_arr = (int*)(W + o); o += (size_t)LL * RR;
  int* o_arr = (int*)(W + o); o += (size_t)LL * RR;
  float* xfb    = W + o; o += (size_t)64 * GD;
  float* gates  = W + o; o += (size_t)RR * GD;        // aliased: hdp[2] + outp[4] (disjoint)
  float* h2[2]; h2[0] = W + o; o += (size_t)RR * HD_; h2[1] = W + o; o += (size_t)RR * HD_;
  float* c2[2]; c2[0] = W + o; o += (size_t)RR * HD_; c2[1] = W + o; o += (size_t)RR * HD_;
  size_t needed_bytes = o * sizeof(float);
  float* logpb[2] = {logpb0, logpb1};
  float* hdp  = gates;                      // 2 x RR*HD_ = 1,048,576 floats
  float* outp = gates + (size_t)2 * RR * HD_;  // 4 x RR*VV = 819,200 floats (disjoint from hdp)

  if (ws_size < needed_bytes) {
    rA_flag<<<(OUT_N + 255) / 256, 256, 0, stream>>>(out);
    return;
  }

  rA_wszero<<<2048, 256, 0, stream>>>(h2[0], c2[0], Gv, logpb[0], accum);
  rA_xfb<<<64, 256, 0, stream>>>(x_feat, W_ih, b_ih, b_hh, xfb);

  for (int t = 0; t < LL; ++t) {
    int pi = t & 1, po = pi ^ 1;
    rA_glstm<<<dim3(16, 8, 4), 128, 0, stream>>>(h2[pi], W_hh, W_ih, W_in_op, b_in_op,
                                                 s_arr, o_arr, t, gates);
    rA_lstm<<<2048, 256, 0, stream>>>(gates, xfb, c2[pi], o_arr, t, c2[po], h2[po]);
    rA_fc1<<<dim3(16, 8, 2), 128, 0, stream>>>(h2[po], W_fc1, hdp);
    rA_out<<<dim3(7, 8, 4), 128, 0, stream>>>(hdp, b_fc1, W_out, outp);
    rA_smax<<<64, 256, 0, stream>>>(outp, b_out, logpb[pi], logpb[po], Gv,
                                    gum + (size_t)t * RR * VV,
                                    s_arr + (size_t)t * RR, o_arr + (size_t)t * RR,
                                    lv_arr + (size_t)t * RR, accum, out,
                                    t, (t == LL - 1) ? 1 : 0);
  }
  rA_final<<<1, 512, 0, stream>>>(lv_arr, s_arr, o_arr, accum, out);
}

// Round 11
// 2781.211 us; speedup vs baseline: 1.2427x; 1.2427x over previous
//
#include <hip/hip_runtime.h>
#include <hip/hip_bf16.h>
#include <cstdint>

#define RR 512          // B*K rows
#define KB_ 8           // beams
#define VV 400          // vocab
#define HD_ 1024
#define GD 4096         // 4*HD
#define LL 13           // program_len
#define BKT 16          // GEMM K-tile
#define NPTS 1000      // integration points
#define OUT_N 18560
#define LDP 68          // padded LDS leading dim (64-wide tiles)
#define AP 36           // padded leading dim, 32-row A tile
#define BP 132          // padded leading dim, 128-col B tile

// unordered pair tables (j<l) for the 28 off-diagonal logsumexp reductions
__device__ __constant__ int cPJ[28] = {0,0,0,0,0,0,0,1,1,1,1,1,1,2,2,2,2,2,3,3,3,3,4,4,4,5,5,6};
__device__ __constant__ int cPL[28] = {1,2,3,4,5,6,7,2,3,4,5,6,7,3,4,5,6,7,4,5,6,7,5,6,7,6,7,7};

__device__ __forceinline__ float rB_log1mexp(float x) {
  x = fminf(x, -1e-38f);
  return (x > -0.6931472f) ? logf(-expm1f(x)) : log1pf(-expf(x));
}

__device__ __forceinline__ float rB_sigm(float x) { return 1.f / (1.f + expf(-x)); }

__device__ __forceinline__ int rB_pidx(int j, int l) {
  if (j > l) { int t = j; j = l; l = t; }
  return 9 + (j * (15 - j)) / 2 + (l - j - 1);
}

__device__ __forceinline__ float rB_wmax(float v) {
  #pragma unroll
  for (int o = 32; o; o >>= 1) v = fmaxf(v, __shfl_xor(v, o, 64));
  return v;
}

__device__ __forceinline__ float rB_wsum(float v) {
  #pragma unroll
  for (int o = 32; o; o >>= 1) v += __shfl_xor(v, o, 64);
  return v;
}

// ---- zero carried state ----
__global__ __launch_bounds__(256) void rB_wszero(float* h0, float* c0, float* Gv,
                                                 float* logp0, float* accum) {
  int idx = blockIdx.x * 256 + threadIdx.x;
  if (idx < RR * HD_) { h0[idx] = 0.f; c0[idx] = 0.f; }
  if (idx < RR) { Gv[idx] = 0.f; logp0[idx] = 0.f; }
  if (idx < 128) accum[idx] = 0.f;
}

__global__ __launch_bounds__(256) void rB_flag(float* dout) {
  int idx = blockIdx.x * 256 + threadIdx.x;
  if (idx < OUT_N) dout[idx] = (idx == 6656) ? 20000.0f : 0.0f;
}

// xfb once
__global__ __launch_bounds__(256) void rB_xfb(const float* __restrict__ xf,
                                              const float* __restrict__ Wih,
                                              const float* __restrict__ bih,
                                              const float* __restrict__ bhh,
                                              float* __restrict__ xfb) {
  __shared__ __align__(16) float As[BKT][LDP];
  __shared__ __align__(16) float Bs[BKT][LDP];
  float acc[4][4] = {};
  const int tid = threadIdx.x;
  const int n0 = blockIdx.x * 64;
  const int la = tid >> 2, lk = (tid & 3) << 2;
  const int tx = tid & 15, ty = tid >> 4;
  for (int k0 = 0; k0 < 1024; k0 += BKT) {
    float4 av = *reinterpret_cast<const float4*>(xf + (size_t)la * 1024 + k0 + lk);
    float4 bv = *reinterpret_cast<const float4*>(Wih + (size_t)(n0 + la) * 1152 + k0 + lk);
    __syncthreads();
    As[lk + 0][la] = av.x; As[lk + 1][la] = av.y; As[lk + 2][la] = av.z; As[lk + 3][la] = av.w;
    Bs[lk + 0][la] = bv.x; Bs[lk + 1][la] = bv.y; Bs[lk + 2][la] = bv.z; Bs[lk + 3][la] = bv.w;
    __syncthreads();
    #pragma unroll
    for (int kk = 0; kk < BKT; ++kk) {
      float4 a = *reinterpret_cast<const float4*>(&As[kk][ty * 4]);
      float4 b = *reinterpret_cast<const float4*>(&Bs[kk][tx * 4]);
      float ar[4] = {a.x, a.y, a.z, a.w};
      float br[4] = {b.x, b.y, b.z, b.w};
      #pragma unroll
      for (int i = 0; i < 4; ++i)
        #pragma unroll
        for (int j = 0; j < 4; ++j)
          acc[i][j] = fmaf(ar[i], br[j], acc[i][j]);
    }
  }
  #pragma unroll
  for (int i = 0; i < 4; ++i)
    #pragma unroll
    for (int j = 0; j < 4; ++j) {
      int r = ty * 4 + i, c = n0 + tx * 4 + j;
      xfb[(size_t)r * GD + c] = acc[i][j] + bih[c] + bhh[c];
    }
}

// gates GEMM (r9-winning shape): 32r x 128c x 1 gate, 256 threads; grid (8,16,4).
// A rows gathered via parent order; inp operand inline (one-hot column gather).
__global__ __launch_bounds__(256) void rB_glstm(
    const float* __restrict__ hprev,
    const float* __restrict__ Whh, const float* __restrict__ Wih,
    const float* __restrict__ Wio, const float* __restrict__ bio,
    const int* __restrict__ s_arr, const int* __restrict__ o_arr, int t,
    float* __restrict__ gates)
{
  __shared__ __align__(16) float As[BKT][AP];
  __shared__ __align__(16) float Bs[BKT][BP];
  float acc[4][4] = {};
  const int tid = threadIdx.x;
  const int c0 = blockIdx.x * 128;        // col offset within gate
  const int r0 = blockIdx.y * 32;
  const int g  = blockIdx.z;
  const int a_r = tid >> 3;               // 0..31
  const int a_k = (tid & 7) * 2;          // 0,2,..,14
  const int b_r = tid >> 1;               // 0..127
  const int b_k = (tid & 1) * 8;          // 0 or 8
  const int tx = tid & 31, ty = tid >> 5; // cols tx*4, rows ty*4
  const int arow = r0 + a_r;
  const int asrc = (t == 0) ? arow : o_arr[(size_t)(t - 1) * RR + arow];
  const int s_row = (t == 0) ? 400 : s_arr[(size_t)(t - 1) * RR + arow];
  const float* Arow  = hprev + (size_t)asrc * HD_;
  const float* BrowW = Whh + (size_t)(g * 1024 + c0 + b_r) * HD_;
  for (int k0 = 0; k0 < HD_; k0 += BKT) {
    float2 av = *reinterpret_cast<const float2*>(Arow + k0 + a_k);
    float4 b0 = *reinterpret_cast<const float4*>(BrowW + k0 + b_k);
    float4 b1 = *reinterpret_cast<const float4*>(BrowW + k0 + b_k + 4);
    __syncthreads();
    As[a_k][a_r] = av.x; As[a_k + 1][a_r] = av.y;
    Bs[b_k + 0][b_r] = b0.x; Bs[b_k + 1][b_r] = b0.y;
    Bs[b_k + 2][b_r] = b0.z; Bs[b_k + 3][b_r] = b0.w;
    Bs[b_k + 4][b_r] = b1.x; Bs[b_k + 5][b_r] = b1.y;
    Bs[b_k + 6][b_r] = b1.z; Bs[b_k + 7][b_r] = b1.w;
    __syncthreads();
    #pragma unroll
    for (int kk = 0; kk < BKT; ++kk) {
      float4 a = *reinterpret_cast<const float4*>(&As[kk][ty * 4]);
      float4 b = *reinterpret_cast<const float4*>(&Bs[kk][tx * 4]);
      float ar[4] = {a.x, a.y, a.z, a.w};
      float br[4] = {b.x, b.y, b.z, b.w};
      #pragma unroll
      for (int i = 0; i < 4; ++i)
        #pragma unroll
        for (int j = 0; j < 4; ++j)
          acc[i][j] = fmaf(ar[i], br[j], acc[i][j]);
    }
  }
  // inp part: K=128; A element = relu(Wio[m*401 + s_row] + bio[m]), rows NOT gathered
  const float* BrowI = Wih + (size_t)(g * 1024 + c0 + b_r) * 1152 + 1024;
  for (int k0 = 0; k0 < 128; k0 += BKT) {
    int m0 = k0 + a_k;
    float a0 = fmaxf(Wio[(size_t)m0 * 401 + s_row] + bio[m0], 0.f);
    float a1 = fmaxf(Wio[(size_t)(m0 + 1) * 401 + s_row] + bio[m0 + 1], 0.f);
    float4 b0 = *reinterpret_cast<const float4*>(BrowI + k0 + b_k);
    float4 b1 = *reinterpret_cast<const float4*>(BrowI + k0 + b_k + 4);
    __syncthreads();
    As[a_k][a_r] = a0; As[a_k + 1][a_r] = a1;
    Bs[b_k + 0][b_r] = b0.x; Bs[b_k + 1][b_r] = b0.y;
    Bs[b_k + 2][b_r] = b0.z; Bs[b_k + 3][b_r] = b0.w;
    Bs[b_k + 4][b_r] = b1.x; Bs[b_k + 5][b_r] = b1.y;
    Bs[b_k + 6][b_r] = b1.z; Bs[b_k + 7][b_r] = b1.w;
    __syncthreads();
    #pragma unroll
    for (int kk = 0; kk < BKT; ++kk) {
      float4 a = *reinterpret_cast<const float4*>(&As[kk][ty * 4]);
      float4 b = *reinterpret_cast<const float4*>(&Bs[kk][tx * 4]);
      float ar[4] = {a.x, a.y, a.z, a.w};
      float br[4] = {b.x, b.y, b.z, b.w};
      #pragma unroll
      for (int i = 0; i < 4; ++i)
        #pragma unroll
        for (int j = 0; j < 4; ++j)
          acc[i][j] = fmaf(ar[i], br[j], acc[i][j]);
    }
  }
  #pragma unroll
  for (int i = 0; i < 4; ++i)
    #pragma unroll
    for (int j = 0; j < 4; ++j)
      gates[(size_t)(r0 + ty * 4 + i) * GD + g * 1024 + c0 + tx * 4 + j] = acc[i][j];
}

// LSTM pointwise: + xfb, gathered c_prev
__global__ __launch_bounds__(256) void rB_lstm(const float* gates, const float* xfb,
                                               const float* cprev, const int* o_arr, int t,
                                               float* cout, float* hout) {
  int idx = blockIdx.x * 256 + threadIdx.x;   // 512*1024
  int r = idx >> 10, n = idx & 1023;
  int src = (t == 0) ? r : o_arr[(size_t)(t - 1) * RR + r];
  const float* g = gates + (size_t)r * GD;
  const float* xb = xfb + (size_t)(r & 63) * GD;
  float gi = g[n] + xb[n];
  float gf = g[1024 + n] + xb[1024 + n];
  float gg = g[2048 + n] + xb[2048 + n];
  float go = g[3072 + n] + xb[3072 + n];
  float cp = cprev[(size_t)src * HD_ + n];
  float c = rB_sigm(gf) * cp + rB_sigm(gi) * tanhf(gg);
  cout[idx] = c;
  hout[idx] = rB_sigm(go) * tanhf(c);
}

// fc1 K-split (r9 shape): grid (16,8,2), 256 thr; partial -> hdp[z]
__global__ __launch_bounds__(256) void rB_fc1(const float* __restrict__ h,
                                              const float* __restrict__ W1, float* hdp) {
  __shared__ __align__(16) float As[BKT][LDP];
  __shared__ __align__(16) float Bs[BKT][LDP];
  float acc[4][4] = {};
  const int tid = threadIdx.x;
  const int n0 = blockIdx.x * 64, r0 = blockIdx.y * 64, z = blockIdx.z;
  const int la = tid >> 2, lk = (tid & 3) << 2;
  const int tx = tid & 15, ty = tid >> 4;
  const float* Arow = h + (size_t)(r0 + la) * HD_ + z * 512;
  const float* Brow = W1 + (size_t)(n0 + la) * HD_ + z * 512;
  for (int k0 = 0; k0 < 512; k0 += BKT) {
    float4 av = *reinterpret_cast<const float4*>(Arow + k0 + lk);
    float4 bv = *reinterpret_cast<const float4*>(Brow + k0 + lk);
    __syncthreads();
    As[lk + 0][la] = av.x; As[lk + 1][la] = av.y; As[lk + 2][la] = av.z; As[lk + 3][la] = av.w;
    Bs[lk + 0][la] = bv.x; Bs[lk + 1][la] = bv.y; Bs[lk + 2][la] = bv.z; Bs[lk + 3][la] = bv.w;
    __syncthreads();
    #pragma unroll
    for (int kk = 0; kk < BKT; ++kk) {
      float4 a = *reinterpret_cast<const float4*>(&As[kk][ty * 4]);
      float4 b = *reinterpret_cast<const float4*>(&Bs[kk][tx * 4]);
      float ar[4] = {a.x, a.y, a.z, a.w};
      float br[4] = {b.x, b.y, b.z, b.w};
      #pragma unroll
      for (int i = 0; i < 4; ++i)
        #pragma unroll
        for (int j = 0; j < 4; ++j)
          acc[i][j] = fmaf(ar[i], br[j], acc[i][j]);
    }
  }
  float* dst = hdp + (size_t)z * RR * HD_;
  #pragma unroll
  for (int i = 0; i < 4; ++i)
    #pragma unroll
    for (int j = 0; j < 4; ++j)
      dst[(size_t)(r0 + ty * 4 + i) * HD_ + n0 + tx * 4 + j] = acc[i][j];
}

// out K-split (r9 shape + relu fold): grid (7,8,4), 256 thr; A = relu(hdp0+hdp1+b1).
__global__ __launch_bounds__(256) void rB_out(const float* __restrict__ hdp,
                                              const float* __restrict__ b1,
                                              const float* __restrict__ Wo, float* outp) {
  __shared__ __align__(16) float As[BKT][LDP];
  __shared__ __align__(16) float Bs[BKT][LDP];
  float acc[4][4] = {};
  const int tid = threadIdx.x;
  const int n0 = blockIdx.x * 64, r0 = blockIdx.y * 64, z = blockIdx.z;
  const int la = tid >> 2, lk = (tid & 3) << 2;
  const int tx = tid & 15, ty = tid >> 4;
  const size_t aoff = (size_t)(r0 + la) * HD_ + z * 256;
  const int bcol = n0 + la;
  const float* Brow = Wo + (size_t)bcol * HD_ + z * 256;
  for (int k0 = 0; k0 < 256; k0 += BKT) {
    float4 h0 = *reinterpret_cast<const float4*>(hdp + aoff + k0 + lk);
    float4 h1 = *reinterpret_cast<const float4*>(hdp + RR * HD_ + aoff + k0 + lk);
    float4 bb = *reinterpret_cast<const float4*>(b1 + z * 256 + k0 + lk);
    float4 av = make_float4(fmaxf(h0.x + h1.x + bb.x, 0.f),
                            fmaxf(h0.y + h1.y + bb.y, 0.f),
                            fmaxf(h0.z + h1.z + bb.z, 0.f),
                            fmaxf(h0.w + h1.w + bb.w, 0.f));
    float4 bv = make_float4(0.f, 0.f, 0.f, 0.f);
    if (bcol < VV)
      bv = *reinterpret_cast<const float4*>(Brow + k0 + lk);
    __syncthreads();
    As[lk + 0][la] = av.x; As[lk + 1][la] = av.y; As[lk + 2][la] = av.z; As[lk + 3][la] = av.w;
    Bs[lk + 0][la] = bv.x; Bs[lk + 1][la] = bv.y; Bs[lk + 2][la] = bv.z; Bs[lk + 3][la] = bv.w;
    __syncthreads();
    #pragma unroll
    for (int kk = 0; kk < BKT; ++kk) {
      float4 a = *reinterpret_cast<const float4*>(&As[kk][ty * 4]);
      float4 b = *reinterpret_cast<const float4*>(&Bs[kk][tx * 4]);
      float ar[4] = {a.x, a.y, a.z, a.w};
      float br[4] = {b.x, b.y, b.z, b.w};
      #pragma unroll
      for (int i = 0; i < 4; ++i)
        #pragma unroll
        for (int j = 0; j < 4; ++j)
          acc[i][j] = fmaf(ar[i], br[j], acc[i][j]);
    }
  }
  float* base = outp + (size_t)z * RR * VV;
  #pragma unroll
  for (int i = 0; i < 4; ++i)
    #pragma unroll
    for (int j = 0; j < 4; ++j) {
      int c = n0 + tx * 4 + j;
      if (c < VV) base[(size_t)(r0 + ty * 4 + i) * VV + c] = acc[i][j];
    }
}

// pack (value, index) so u64-max == (max value, tie -> lower index)
__device__ __forceinline__ unsigned long long rB_pack(float v, int c) {
  unsigned u = __float_as_uint(v);
  u = (u & 0x80000000u) ? ~u : (u | 0x80000000u);
  return ((unsigned long long)u << 32) | (unsigned)(0xFFFFFFFFu - (unsigned)c);
}

// fused per-batch: logit-combine + log_softmax + entropy + gumbel-with-max
// + top-8 + selection bookkeeping + compute_log_R + entropy accumulation.
__global__ __launch_bounds__(256) void rB_smax(
    const float* __restrict__ outp, const float* __restrict__ bo,
    const float* __restrict__ logp_in, float* logp_out, float* Gv,
    const float* __restrict__ gum, int* s_t, int* o_t, float* lv_t,
    float* accum, float* dout, int t, int last)
{
  __shared__ __align__(16) float shbuf[9000];   // A: gk[3200]+lpl[3200]; B: Tm[8][1000]+base[1000]
  __shared__ float entold8[KB_], phi8[KB_], entb8[KB_], pj8[KB_];
  __shared__ float res[37];
  __shared__ unsigned long long wbest[4], selK[KB_];
  float* gk  = shbuf;
  float* lpl = shbuf + 3200;
  const int i = blockIdx.x, tid = threadIdx.x;
  const int lane = tid & 63, wid = tid >> 6;

  // ---- soft phase: 2 rows per wave ----
  for (int rl = wid; rl < KB_; rl += 4) {
    int r = rl * 64 + i;
    float lv_[7];
    float m = -INFINITY;
    #pragma unroll
    for (int ch = 0; ch < 7; ++ch) {
      int n = ch * 64 + lane;
      float l = -INFINITY;
      if (n < VV) {
        size_t off = (size_t)r * VV + n;
        l = outp[off] + outp[RR * VV + off] + outp[2 * RR * VV + off]
          + outp[3 * RR * VV + off] + bo[n];
      }
      lv_[ch] = l;
      m = fmaxf(m, l);
    }
    m = rB_wmax(m);
    float ssum = 0.f;
    #pragma unroll
    for (int ch = 0; ch < 7; ++ch) {
      int n = ch * 64 + lane;
      if (n < VV) ssum += expf(lv_[ch] - m);
    }
    ssum = rB_wsum(ssum);
    float ls = logf(ssum);
    float ent = 0.f;
    #pragma unroll
    for (int ch = 0; ch < 7; ++ch) {
      int n = ch * 64 + lane;
      if (n < VV) {
        float lp = lv_[ch] - m - ls;
        lpl[rl * VV + n] = lp;
        ent += lp * expf(lp);
        lv_[ch] = lp;          // reuse: now holds lp
      }
    }
    ent = rB_wsum(ent);
    if (lane == 0) entold8[rl] = ent;
    float lpr = logp_in[r];
    const float* ur = gum + (size_t)r * VV;
    float gp_[7];
    float Z = -INFINITY;
    #pragma unroll
    for (int ch = 0; ch < 7; ++ch) {
      int n = ch * 64 + lane;
      float gp = -INFINITY;
      if (n < VV) {
        float u = ur[n];
        gp = lv_[ch] + lpr - logf(-logf(u * (1.f - 2e-7f) + 1e-7f));
      }
      gp_[ch] = gp;
      Z = fmaxf(Z, gp);
    }
    Z = rB_wmax(Z);
    float T = Gv[r];
    #pragma unroll
    for (int ch = 0; ch < 7; ++ch) {
      int n = ch * 64 + lane;
      if (n < VV) {
        float vv = T - gp_[ch] + rB_log1mexp(gp_[ch] - Z);
        gk[rl * VV + n] = T - fmaxf(vv, 0.f) - log1pf(expf(-fabsf(vv)));
      }
    }
  }
  __syncthreads();

  // ---- topk phase ----
  int limit = (t == 0) ? VV : KB_ * VV;
  for (int it = 0; it < KB_; ++it) {
    unsigned long long b = 0ull;
    for (int c = tid; c < limit; c += 256) {
      unsigned long long k = rB_pack(gk[c], c);
      b = (k > b) ? k : b;
    }
    #pragma unroll
    for (int o = 32; o; o >>= 1) {
      unsigned long long x = __shfl_xor(b, o, 64);
      b = (x > b) ? x : b;
    }
    if (lane == 0) wbest[wid] = b;
    __syncthreads();
    unsigned long long g = wbest[0];
    g = (wbest[1] > g) ? wbest[1] : g;
    g = (wbest[2] > g) ? wbest[2] : g;
    g = (wbest[3] > g) ? wbest[3] : g;
    if (tid == 0) {
      int csel = (int)(0xFFFFFFFFu - (unsigned)(g & 0xFFFFFFFFu));
      gk[csel] = -INFINITY;
      selK[it] = g;
    }
    __syncthreads();
  }

  // ---- selection bookkeeping ----
  if (tid < KB_) {
    unsigned long long g = selK[tid];
    unsigned x = (unsigned)(g >> 32);
    x = (x & 0x80000000u) ? (x & 0x7FFFFFFFu) : ~x;
    float v = __uint_as_float(x);
    int c = (int)(0xFFFFFFFFu - (unsigned)(g & 0xFFFFFFFFu));
    int r = tid * 64 + i;
    int s = c % VV;
    int jp = c / VV;               // local parent beam
    int o = jp * 64 + i;
    Gv[r] = v;
    s_t[r] = s;
    o_t[r] = o;
    float lv = lpl[jp * VV + s];
    float ph = logp_in[o] + lv;
    logp_out[r] = ph;
    lv_t[r] = lv;
    phi8[tid] = ph;
    pj8[tid] = expf(ph);
    entb8[tid] = entold8[jp];
  }
  __syncthreads();

  // ---- logR phase (Tm/base overlay gk/lpl) ----
  float (*Tm)[NPTS] = reinterpret_cast<float (*)[NPTS]>(shbuf);
  float* base = shbuf + 8000;
  float pS = ((pj8[0] + pj8[1]) + (pj8[2] + pj8[3])) + ((pj8[4] + pj8[5]) + (pj8[6] + pj8[7]));
  for (int n = tid; n < NPTS; n += 256) {
    float lu = logf((n + 0.5f) * (1.0f / NPTS));
    float b = -pS * lu;
    #pragma unroll
    for (int j = 0; j < KB_; ++j) {
      float tv = rB_log1mexp(pj8[j] * lu);
      Tm[j][n] = tv; b += tv;
    }
    base[n] = b;
  }
  __syncthreads();
  const float logN = 6.9077552789821f;   // log(1000)
  for (int ridx = wid; ridx < 37; ridx += 4) {
    int jj = -1, ll = -1;
    if (ridx >= 1 && ridx < 9) jj = ridx - 1;
    else if (ridx >= 9) { jj = cPJ[ridx - 9]; ll = cPL[ridx - 9]; }
    float mx = -INFINITY;
    for (int n = lane; n < NPTS; n += 64) {
      float v = base[n];
      if (jj >= 0) v -= Tm[jj][n];
      if (ll >= 0) v -= Tm[ll][n];
      mx = fmaxf(mx, v);
    }
    mx = rB_wmax(mx);
    float sm = 0.f;
    for (int n = lane; n < NPTS; n += 64) {
      float v = base[n];
      if (jj >= 0) v -= Tm[jj][n];
      if (ll >= 0) v -= Tm[ll][n];
      sm += expf(v - mx);
    }
    sm = rB_wsum(sm);
    if (lane == 0) res[ridx] = mx + logf(sm) - logN;
  }
  __syncthreads();
  if (tid == 0) {
    float logI = res[0];
    float Wsum = 0.f, ws = 0.f;
    #pragma unroll
    for (int j = 0; j < KB_; ++j) {
      float lRs = res[1 + j] - logI;
      float wj = expf(phi8[j] + lRs);
      Wsum += wj;
      ws += wj * entb8[j];
    }
    accum[i] += ws;               // ent_plot
    accum[64 + i] += ws / Wsum;   // entropy_element
    if (last) {
      for (int j = 0; j < KB_; ++j) {
        dout[13376 + i * 8 + j] = res[1 + j] - logI;     // log_R_s
        dout[17984 + i * 8 + j] = phi8[j];               // phi_k
        for (int l = 0; l < KB_; ++l) {
          float v = (l == j) ? 0.f : (res[rB_pidx(j, l)] - res[1 + j]);
          dout[13888 + i * 64 + j * 8 + l] = v;          // log_R_ss
        }
      }
    }
  }
}

// final: walk ancestor chains, pack all outputs (float32)
__global__ __launch_bounds__(512) void rB_final(const float* lv_arr, const int* s_arr,
                                                const int* o_arr, const float* accum,
                                                float* dout) {
  int r = threadIdx.x;
  int i = r & 63, j = r >> 6;
  float vals[LL]; int svs[LL];
  int a = r;
  for (int tt = LL - 1; tt >= 0; --tt) {
    vals[tt] = lv_arr[tt * RR + a];
    svs[tt]  = s_arr[tt * RR + a];
    a = o_arr[tt * RR + a];
  }
  #pragma unroll
  for (int tt = 0; tt < LL; ++tt) {
    dout[i * 104 + j * 13 + tt] = vals[tt];
    dout[6656 + i * 104 + j * 13 + tt] = (float)svs[tt];
  }
  if (r < 64) {
    dout[13312 + r] = accum[64 + r];   // entropy_element
    dout[18496 + r] = accum[r];        // ent_plot
  }
}

extern "C" void kernel_launch(void* const* d_in, const int* in_sizes, int n_in,
                              void* d_out, int out_size, void* d_ws, size_t ws_size,
                              hipStream_t stream) {
  const float* x_feat  = (const float*)d_in[0];
  const float* W_in_op = (const float*)d_in[1];
  const float* b_in_op = (const float*)d_in[2];
  const float* W_ih    = (const float*)d_in[3];
  const float* W_hh    = (const float*)d_in[4];
  const float* b_ih    = (const float*)d_in[5];
  const float* b_hh    = (const float*)d_in[6];
  const float* W_fc1   = (const float*)d_in[7];
  const float* b_fc1   = (const float*)d_in[8];
  const float* W_out   = (const float*)d_in[9];
  const float* b_out   = (const float*)d_in[10];
  const float* gum     = (const float*)d_in[11];
  float* out           = (float*)d_out;

  float* W = (float*)d_ws;
  size_t o = 0;
  float* lv_arr = W + o; o += (size_t)LL * RR;
  float* Gv     = W + o; o += RR;
  float* logpb0 = W + o; o += RR;
  float* logpb1 = W + o; o += RR;
  float* accum  = W + o; o += 128;
  int* s_arr = (int*)(W + o); o += (size_t)LL * RR;
  int* o_arr = (int*)(W + o); o += (size_t)LL * RR;
  float* xfb    = W + o; o += (size_t)64 * GD;
  float* gates  = W + o; o += (size_t)RR * GD;        // aliased with hdp (disjoint from outp)
  float* h2[2]; h2[0] = W + o; o += (size_t)RR * HD_; h2[1] = W + o; o += (size_t)RR * HD_;
  float* c2[2]; c2[0] = W + o; o += (size_t)RR * HD_; c2[1] = W + o; o += (size_t)RR * HD_;
  float* outp   = W + o; o += (size_t)4 * RR * VV;    // out partials (read hdp while writing)
  size_t needed_bytes = o * sizeof(float);
  float* logpb[2] = {logpb0, logpb1};
  float* hdp = gates;                       // 2 x RR*HD_ fc1 partials (gates dead by then)

  if (ws_size < needed_bytes) {
    rB_flag<<<(OUT_N + 255) / 256, 256, 0, stream>>>(out);
    return;
  }

  rB_wszero<<<2048, 256, 0, stream>>>(h2[0], c2[0], Gv, logpb[0], accum);
  rB_xfb<<<64, 256, 0, stream>>>(x_feat, W_ih, b_ih, b_hh, xfb);

  for (int t = 0; t < LL; ++t) {
    int pi = t & 1, po = pi ^ 1;
    rB_glstm<<<dim3(8, 16, 4), 256, 0, stream>>>(h2[pi], W_hh, W_ih, W_in_op, b_in_op,
                                                 s_arr, o_arr, t, gates);
    rB_lstm<<<2048, 256, 0, stream>>>(gates, xfb, c2[pi], o_arr, t, c2[po], h2[po]);
    rB_fc1<<<dim3(16, 8, 2), 256, 0, stream>>>(h2[po], W_fc1, hdp);
    rB_out<<<dim3(7, 8, 4), 256, 0, stream>>>(hdp, b_fc1, W_out, outp);
    rB_smax<<<64, 256, 0, stream>>>(outp, b_out, logpb[pi], logpb[po], Gv,
                                    gum + (size_t)t * RR * VV,
                                    s_arr + (size_t)t * RR, o_arr + (size_t)t * RR,
                                    lv_arr + (size_t)t * RR, accum, out,
                                    t, (t == LL - 1) ? 1 : 0);
  }
  rB_final<<<1, 512, 0, stream>>>(lv_arr, s_arr, o_arr, accum, out);
}